// Round 16
// baseline (421.327 us; speedup 1.0000x reference)
//
#include <hip/hip_runtime.h>
#include <hip/hip_bf16.h>
#include <hip/hip_fp16.h>

typedef unsigned int uint32;
typedef unsigned short u16;

#define TOK 1024
#define HID 2048
#define NEXP 64
#define TOPK 8
#define IMED 768
#define IMED2 1536
#define LSTR 112  // LDS row stride (bytes)

typedef __attribute__((ext_vector_type(8))) _Float16 half8;
typedef __attribute__((ext_vector_type(4))) float f32x4;

static __device__ __forceinline__ uint32 pack2(float a, float b) {
  union { _Float16 h[2]; uint32 u; } p;
  p.h[0] = (_Float16)a; p.h[1] = (_Float16)b;
  return p.u;
}
static __device__ __forceinline__ u16 f2h(float a) {
  union { _Float16 h; u16 u; } p;
  p.h = (_Float16)a;
  return p.u;
}
static __device__ __forceinline__ void bar_nodrain() {
  asm volatile("s_waitcnt lgkmcnt(0)" ::: "memory");
  __builtin_amdgcn_sched_barrier(0);
  __builtin_amdgcn_s_barrier();
}

// ---------------- router: 4 tokens/block; logits -> top8 -> renorm; emits xh
__global__ __launch_bounds__(256) void router_kernel(
    const float* __restrict__ x, const float* __restrict__ gw,
    int* __restrict__ topk_id, float* __restrict__ topk_w,
    u16* __restrict__ xh) {
  int t0 = blockIdx.x << 2;
  __shared__ float part[4][NEXP][5];
  int tid = threadIdx.x;
  int e = tid & 63, p = tid >> 6;
  const float* gwp = gw + (size_t)e * HID + (p << 9);
  const float* xp = x + (size_t)t0 * HID + (p << 9);
  float acc[4] = {0.f, 0.f, 0.f, 0.f};
  for (int i = 0; i < 128; i++) {
    float4 w = ((const float4*)gwp)[i];
    #pragma unroll
    for (int t = 0; t < 4; t++) {
      float4 xv = *(const float4*)(xp + (size_t)t * HID + (i << 2));
      acc[t] += w.x * xv.x + w.y * xv.y + w.z * xv.z + w.w * xv.w;
    }
  }
  #pragma unroll
  for (int t = 0; t < 4; t++) part[p][e][t] = acc[t];
  for (int i = tid; i < 2048; i += 256) {
    int r = i >> 9;
    int c = i & 511;
    float4 v = *(const float4*)(x + (size_t)(t0 + r) * HID + (c << 2));
    uint2 hp;
    hp.x = pack2(v.x, v.y);
    hp.y = pack2(v.z, v.w);
    *(uint2*)(xh + (size_t)(t0 + r) * HID + (c << 2)) = hp;
  }
  __syncthreads();
  int wv = tid >> 6, l = tid & 63;
  int t = t0 + wv;
  float lg = part[0][l][wv] + part[1][l][wv] + part[2][l][wv] + part[3][l][wv];
  float m = lg;
  #pragma unroll
  for (int d = 1; d < 64; d <<= 1) m = fmaxf(m, __shfl_xor(m, d));
  float v = __expf(lg - m);
  float w8[TOPK]; int i8[TOPK]; float wsum = 0.f;
  #pragma unroll
  for (int k = 0; k < TOPK; k++) {
    float bv = v; int bi = l;
    #pragma unroll
    for (int d = 1; d < 64; d <<= 1) {
      float ov = __shfl_xor(bv, d);
      int oi = __shfl_xor(bi, d);
      if (ov > bv || (ov == bv && oi < bi)) { bv = ov; bi = oi; }
    }
    w8[k] = bv; i8[k] = bi; wsum += bv;
    if (l == bi) v = -1.f;
  }
  if (l == 0) {
    float rinv = 1.f / wsum;
    #pragma unroll
    for (int k = 0; k < TOPK; k++) {
      topk_id[t * TOPK + k] = i8[k];
      topk_w[t * TOPK + k] = w8[k] * rinv;
    }
  }
}

// ------- per-expert scatter (64 blocks), self-counting, no memset ----------
__global__ __launch_bounds__(256) void scatter_kernel(
    const int* __restrict__ topk_id, const float* __restrict__ topk_w,
    int* __restrict__ off, int* __restrict__ gcnt,
    int* __restrict__ row_tok, float* __restrict__ row_w,
    int* __restrict__ inv) {
  int e = blockIdx.x;
  __shared__ int lcnt[NEXP];
  __shared__ int sbase;
  __shared__ int scur;
  int tid = threadIdx.x;
  if (tid < NEXP) lcnt[tid] = 0;
  __syncthreads();
  for (int i = tid; i < TOK * TOPK; i += 256) atomicAdd(&lcnt[topk_id[i]], 1);
  __syncthreads();
  if (tid < 64) {
    int c = lcnt[tid];
    int xv = c;
    #pragma unroll
    for (int d = 1; d < 64; d <<= 1) {
      int y = __shfl_up(xv, d);
      if (tid >= d) xv += y;
    }
    if (tid == e) {
      sbase = xv - c;
      off[e] = xv - c;
      gcnt[e] = c;
    }
    if (tid == 0) scur = 0;
  }
  __syncthreads();
  int base = sbase;
  for (int i = tid; i < TOK * TOPK; i += 256) {
    if (topk_id[i] == e) {
      int p = atomicAdd(&scur, 1);
      row_tok[base + p] = i >> 3;
      row_w[base + p] = topk_w[i];
      inv[i] = base + p;
    }
  }
}

// ---------------- grouped gate_up GEMM + fused SwiGLU ----------------
// BM=256, BN=48 gate + 48 up, BK=32, 256 threads (4 waves, 4m x 1n)
// 2 blocks/CU, stride-112 LDS, B 2-deep prefetch, non-draining barriers
__global__ __launch_bounds__(256, 2) void gateup_kernel(
    const u16* __restrict__ xh, const float* __restrict__ Wgu,
    const int* __restrict__ off, const int* __restrict__ cnt,
    const int* __restrict__ row_tok, u16* __restrict__ act) {
  int bid = blockIdx.x;                 // 1024 blocks
  int xcd = bid & 7, s2 = bid >> 3;
  int e = xcd + ((s2 & 7) << 3);        // expert pinned to XCD
  int slab = s2 >> 3;                   // 0..15
  int r0 = off[e];
  int ne = cnt[e];
  int c0 = slab * 48;

  __shared__ __align__(16) char AsB[256 * LSTR];  // 28 KB
  __shared__ __align__(16) char BsB[96 * LSTR];   // 10.5 KB

  int tid = threadIdx.x;
  int lane = tid & 63;
  int wm = tid >> 6;                    // 4 M-waves
  int fr = lane & 15, hi = lane >> 4;

  // A stage: 1 thread/row, 32 f16 (4 granules)
  int arow = tid;
  int tok = row_tok[r0 + ((arow < ne) ? arow : 0)];
  const u16* xa = xh + (size_t)tok * HID;

  // B stage: 192 threads; thread -> 1 col x 16 k
  bool bact = tid < 192;
  int bc = tid % 96;                    // 0..47 gate, 48..95 up
  int bkh = tid / 96;                   // 0..1
  int gcol = (bc < 48) ? (c0 + bc) : (IMED + c0 + (bc - 48));
  const float* wb = Wgu + (size_t)e * ((size_t)HID * IMED2) +
                    (size_t)(bkh << 4) * IMED2 + gcol;

  f32x4 accg[4][3], accu[4][3];
  #pragma unroll
  for (int a = 0; a < 4; a++)
    #pragma unroll
    for (int b = 0; b < 3; b++) { accg[a][b] = (f32x4)0.f; accu[a][b] = (f32x4)0.f; }

  uint4 qa0, qa1, qa2, qa3;
  float wv0[16], wv1[16];
  auto LOADA = [&]() {
    const uint4* p = (const uint4*)xa;
    qa0 = p[0]; qa1 = p[1]; qa2 = p[2]; qa3 = p[3];
    xa += 32;
  };
  auto LOADB = [&](float* wv) {
    if (bact) {
      #pragma unroll
      for (int j = 0; j < 16; j++) wv[j] = wb[(size_t)j * IMED2];
    }
    wb += (size_t)32 * IMED2;
  };
  auto STORET = [&](const float* wv) {
    char* A_ = AsB + arow * LSTR;
    *(uint4*)(A_) = qa0;
    *(uint4*)(A_ + 16) = qa1;
    *(uint4*)(A_ + 32) = qa2;
    *(uint4*)(A_ + 48) = qa3;
    if (bact) {
      uint4 u0, u1;
      u0.x = pack2(wv[0], wv[1]);  u0.y = pack2(wv[2], wv[3]);
      u0.z = pack2(wv[4], wv[5]);  u0.w = pack2(wv[6], wv[7]);
      u1.x = pack2(wv[8], wv[9]);  u1.y = pack2(wv[10], wv[11]);
      u1.z = pack2(wv[12], wv[13]); u1.w = pack2(wv[14], wv[15]);
      char* B_ = BsB + bc * LSTR + (bkh << 5);
      *(uint4*)(B_) = u0;
      *(uint4*)(B_ + 16) = u1;
    }
  };
  auto COMPUTE = [&]() {
    half8 af[4];
    #pragma unroll
    for (int mi = 0; mi < 4; mi++) {
      int r = (wm << 6) + (mi << 4) + fr;
      af[mi] = *(half8*)(AsB + r * LSTR + (hi << 4));
    }
    #pragma unroll
    for (int ni = 0; ni < 3; ni++) {
      int ng = (ni << 4) + fr;
      half8 bg = *(half8*)(BsB + ng * LSTR + (hi << 4));
      half8 bu = *(half8*)(BsB + (ng + 48) * LSTR + (hi << 4));
      #pragma unroll
      for (int mi = 0; mi < 4; mi++) {
        accg[mi][ni] = __builtin_amdgcn_mfma_f32_16x16x32_f16(af[mi], bg, accg[mi][ni], 0, 0, 0);
        accu[mi][ni] = __builtin_amdgcn_mfma_f32_16x16x32_f16(af[mi], bu, accu[mi][ni], 0, 0, 0);
      }
    }
  };

  const int NK = HID / 32;  // 64 (even)
  LOADA(); LOADB(wv0);
  STORET(wv0);
  LOADA(); LOADB(wv1);
  LOADB(wv0);
  __syncthreads();

  for (int t = 0; t < NK; t += 2) {
    COMPUTE();                               // tile t
    bar_nodrain();
    if (t + 1 < NK) {
      STORET(wv1);                           // tile t+1
      if (t + 2 < NK) LOADA();               // A t+2
      if (t + 3 < NK) LOADB(wv1);            // B t+3
      bar_nodrain();
    }
    if (t + 1 < NK) {
      COMPUTE();                             // tile t+1
      bar_nodrain();
      if (t + 2 < NK) {
        STORET(wv0);                         // tile t+2
        if (t + 3 < NK) LOADA();             // A t+3
        if (t + 4 < NK) LOADB(wv0);          // B t+4
        bar_nodrain();
      }
    }
  }

  #pragma unroll
  for (int mi = 0; mi < 4; mi++) {
    #pragma unroll
    for (int ni = 0; ni < 3; ni++) {
      int col = c0 + (ni << 4) + fr;
      #pragma unroll
      for (int r = 0; r < 4; r++) {
        int rr = (wm << 6) + (mi << 4) + (hi << 2) + r;
        if (rr < ne) {
          float g = accg[mi][ni][r];
          float u = accu[mi][ni][r];
          float s = g / (1.f + __expf(-g)) * u;
          act[(size_t)(r0 + rr) * IMED + col] = f2h(s);
        }
      }
    }
  }
}

// ---------------- grouped down GEMM -> f16 scratch (no atomics) ------------
// BM=256, BN=128, BK=32, 256 threads (4 waves, 4m x 1n), 2 blocks/CU
__global__ __launch_bounds__(256, 2) void down_kernel(
    const u16* __restrict__ act, const float* __restrict__ Wd,
    const int* __restrict__ off, const int* __restrict__ cnt,
    const float* __restrict__ row_w, u16* __restrict__ dscr) {
  int bid = blockIdx.x;                 // 1024 blocks
  int xcd = bid & 7, s2 = bid >> 3;
  int e = xcd + ((s2 & 7) << 3);
  int slab = s2 >> 3;                   // 0..15
  int r0 = off[e];
  int ne = cnt[e];
  int n0 = slab << 7;

  __shared__ __align__(16) char AsB[256 * LSTR];  // 28 KB
  __shared__ __align__(16) char BsB[128 * LSTR];  // 14 KB

  int tid = threadIdx.x;
  int lane = tid & 63;
  int wm = tid >> 6;
  int fr = lane & 15, hi = lane >> 4;

  // A stage: 1 thread/row, 32 f16 from act
  int arow = tid;
  const u16* ap = act + (size_t)(r0 + ((arow < ne) ? arow : 0)) * IMED;

  // B stage: all 256 threads; thread -> 1 col x 16 k
  int bc = tid & 127;
  int bkh = tid >> 7;
  const float* wb = Wd + (size_t)e * ((size_t)IMED * HID) +
                    (size_t)(bkh << 4) * HID + n0 + bc;

  f32x4 acc[4][8];
  #pragma unroll
  for (int a = 0; a < 4; a++)
    #pragma unroll
    for (int b = 0; b < 8; b++) acc[a][b] = (f32x4)0.f;

  uint4 qa0, qa1, qa2, qa3;
  float wv0[16], wv1[16];
  auto LOADA = [&]() {
    const uint4* p = (const uint4*)ap;
    qa0 = p[0]; qa1 = p[1]; qa2 = p[2]; qa3 = p[3];
    ap += 32;
  };
  auto LOADB = [&](float* wv) {
    #pragma unroll
    for (int j = 0; j < 16; j++) wv[j] = wb[(size_t)j * HID];
    wb += (size_t)32 * HID;
  };
  auto STORET = [&](const float* wv) {
    char* A_ = AsB + arow * LSTR;
    *(uint4*)(A_) = qa0;
    *(uint4*)(A_ + 16) = qa1;
    *(uint4*)(A_ + 32) = qa2;
    *(uint4*)(A_ + 48) = qa3;
    uint4 u0, u1;
    u0.x = pack2(wv[0], wv[1]);  u0.y = pack2(wv[2], wv[3]);
    u0.z = pack2(wv[4], wv[5]);  u0.w = pack2(wv[6], wv[7]);
    u1.x = pack2(wv[8], wv[9]);  u1.y = pack2(wv[10], wv[11]);
    u1.z = pack2(wv[12], wv[13]); u1.w = pack2(wv[14], wv[15]);
    char* B_ = BsB + bc * LSTR + (bkh << 5);
    *(uint4*)(B_) = u0;
    *(uint4*)(B_ + 16) = u1;
  };
  auto COMPUTE = [&]() {
    half8 af[4];
    #pragma unroll
    for (int mi = 0; mi < 4; mi++) {
      int r = (wm << 6) + (mi << 4) + fr;
      af[mi] = *(half8*)(AsB + r * LSTR + (hi << 4));
    }
    #pragma unroll
    for (int ni = 0; ni < 8; ni++) {
      int n = (ni << 4) + fr;
      half8 bf_ = *(half8*)(BsB + n * LSTR + (hi << 4));
      #pragma unroll
      for (int mi = 0; mi < 4; mi++)
        acc[mi][ni] = __builtin_amdgcn_mfma_f32_16x16x32_f16(af[mi], bf_, acc[mi][ni], 0, 0, 0);
    }
  };

  const int NK = IMED / 32;  // 24 (even)
  LOADA(); LOADB(wv0);
  STORET(wv0);
  LOADA(); LOADB(wv1);
  LOADB(wv0);
  __syncthreads();

  for (int t = 0; t < NK; t += 2) {
    COMPUTE();                               // tile t
    bar_nodrain();
    if (t + 1 < NK) {
      STORET(wv1);                           // tile t+1
      if (t + 2 < NK) LOADA();
      if (t + 3 < NK) LOADB(wv1);
      bar_nodrain();
    }
    if (t + 1 < NK) {
      COMPUTE();                             // tile t+1
      bar_nodrain();
      if (t + 2 < NK) {
        STORET(wv0);                         // tile t+2
        if (t + 3 < NK) LOADA();
        if (t + 4 < NK) LOADB(wv0);
        bar_nodrain();
      }
    }
  }

  #pragma unroll
  for (int mi = 0; mi < 4; mi++) {
    #pragma unroll
    for (int r = 0; r < 4; r++) {
      int rr = (wm << 6) + (mi << 4) + (hi << 2) + r;
      if (rr < ne) {
        float w = row_w[r0 + rr];
        #pragma unroll
        for (int ni = 0; ni < 8; ni++) {
          int col = n0 + (ni << 4) + fr;
          dscr[(size_t)(r0 + rr) * HID + col] = f2h(acc[mi][ni][r] * w);
        }
      }
    }
  }
}

// ---------------- combine: out[t] = sum_k dscr[inv[t*8+k]] ------------------
__global__ __launch_bounds__(256) void combine_kernel(
    const u16* __restrict__ dscr, const int* __restrict__ inv,
    float* __restrict__ out) {
  int t = blockIdx.x;
  int c0 = threadIdx.x << 3;
  int rows[TOPK];
  #pragma unroll
  for (int k = 0; k < TOPK; k++) rows[k] = inv[t * TOPK + k];
  float s[8] = {0.f, 0.f, 0.f, 0.f, 0.f, 0.f, 0.f, 0.f};
  #pragma unroll
  for (int k = 0; k < TOPK; k++) {
    union { uint4 q; _Float16 h[8]; } u;
    u.q = *(const uint4*)(dscr + (size_t)rows[k] * HID + c0);
    #pragma unroll
    for (int j = 0; j < 8; j++) s[j] += (float)u.h[j];
  }
  float4 o0 = {s[0], s[1], s[2], s[3]};
  float4 o1 = {s[4], s[5], s[6], s[7]};
  *(float4*)(out + (size_t)t * HID + c0) = o0;
  *(float4*)(out + (size_t)t * HID + c0 + 4) = o1;
}

// ---------------- launch ----------------
extern "C" void kernel_launch(void* const* d_in, const int* in_sizes, int n_in,
                              void* d_out, int out_size, void* d_ws, size_t ws_size,
                              hipStream_t stream) {
  const float* x = (const float*)d_in[0];
  const float* gw = (const float*)d_in[1];
  const float* wgu = (const float*)d_in[2];
  const float* wd = (const float*)d_in[3];
  float* out = (float*)d_out;
  char* ws = (char*)d_ws;

  int* gcnt = (int*)(ws + 0);
  int* off = (int*)(ws + 512);
  int* topk_id = (int*)(ws + 1024);
  float* topk_w = (float*)(ws + 1024 + 32768);
  int* row_tok = (int*)(ws + 1024 + 65536);
  float* row_w = (float*)(ws + 1024 + 98304);
  u16* act = (u16*)(ws + 135168);                                   // 12.6 MB
  u16* xh = (u16*)(ws + 135168 + 12582912);                         // 4 MB
  int* inv = (int*)(ws + 135168 + 12582912 + 4194304);              // 32 KB
  u16* dscr = (u16*)(ws + 135168 + 12582912 + 4194304 + 32768);     // 33.5 MB

  router_kernel<<<TOK / 4, 256, 0, stream>>>(x, gw, topk_id, topk_w, xh);
  scatter_kernel<<<NEXP, 256, 0, stream>>>(topk_id, topk_w, off, gcnt, row_tok, row_w, inv);
  gateup_kernel<<<1024, 256, 0, stream>>>(xh, wgu, off, gcnt, row_tok, act);
  down_kernel<<<1024, 256, 0, stream>>>(act, wd, off, gcnt, row_w, dscr);
  combine_kernel<<<TOK, 256, 0, stream>>>(dscr, inv, out);
}